// Round 1
// baseline (1085.580 us; speedup 1.0000x reference)
//
#include <hip/hip_runtime.h>

#define NNODES 50000
#define NEDGES 500000
#define DIM    160
#define NHEAD  5
#define MLPH   50

typedef __bf16 bf16x8 __attribute__((ext_vector_type(8)));
typedef float  f32x4  __attribute__((ext_vector_type(4)));

// ---- canonical bf16 param block offsets (elements) ----
#define PB_WLT   0
#define PB_WRT   25600
#define PB_WET   51200
#define PB_W1    76800
#define PB_W2    84800
#define PB_VEC   92800      // bl,br,att,bias,g1,beta1,b2,g2,beta2 (9 x 160)
#define PB_SMALL 94240      // b1(50), gm(50), bm(50)
#define PB_TOTAL 94400

struct Ptrs {
    const void *Wl, *Wr, *We;
    const void *bl, *br, *att, *bias, *g1, *beta1;
    const void *W1, *b1, *gm, *bm, *W2, *b2, *g2, *beta2;
};

__device__ __forceinline__ float ldany(const void* p, long i, bool f32) {
    return f32 ? ((const float*)p)[i] : (float)(((const __bf16*)p)[i]);
}

// Decide whether float tensors are f32 or bf16 bit patterns.
__global__ void detect_kernel(const unsigned short* __restrict__ xs, int* __restrict__ flag) {
    __shared__ int red[4];
    int cnt = 0;
    for (int i = threadIdx.x; i < 65536; i += 256) {
        unsigned e = (xs[i] >> 7) & 0xFFu;
        if (e >= 137u) cnt++;
    }
    for (int off = 1; off < 64; off <<= 1) cnt += __shfl_xor(cnt, off, 64);
    if ((threadIdx.x & 63) == 0) red[threadIdx.x >> 6] = cnt;
    __syncthreads();
    if (threadIdx.x == 0) flag[0] = (red[0] + red[1] + red[2] + red[3] > 1000) ? 1 : 0;
}

// Build canonical bf16 param block: W^T x3, W1, W2, and all bias/scale vectors.
__global__ void prep_kernel(Ptrs p, __bf16* __restrict__ pb, const int* __restrict__ flag) {
    const bool f32 = flag[0] != 0;
    int i = blockIdx.x * 256 + threadIdx.x;
    if (i < 76800) {                       // three 160x160 transposes
        int which = i / 25600, r = i - which * 25600;
        int n = r / DIM, k = r - n * DIM;
        const void* w = which == 0 ? p.Wl : which == 1 ? p.Wr : p.We;
        pb[i] = (__bf16)ldany(w, (long)k * DIM + n, f32);
    } else if (i < 84800) {
        pb[i] = (__bf16)ldany(p.W1, i - PB_W1, f32);
    } else if (i < 92800) {
        pb[i] = (__bf16)ldany(p.W2, i - PB_W2, f32);
    } else if (i < 94240) {
        int t = i - PB_VEC, which = t / DIM, off = t - which * DIM;
        const void* v = which == 0 ? p.bl : which == 1 ? p.br : which == 2 ? p.att :
                        which == 3 ? p.bias : which == 4 ? p.g1 : which == 5 ? p.beta1 :
                        which == 6 ? p.b2 : which == 7 ? p.g2 : p.beta2;
        pb[i] = (__bf16)ldany(v, off, f32);
    } else if (i < 94390) {
        int t = i - PB_SMALL;
        const void* v = t < 50 ? p.b1 : t < 100 ? p.gm : p.bm;
        pb[i] = (__bf16)ldany(v, t % 50, f32);
    }
}

// C[M,160] = A[M,160] @ B[160,160] (+bias) via 16x16x32 bf16 MFMA.
// Whole B^T staged in LDS. BM=128 rows/block, 4 waves each own 32 rows x 160 cols.
// DO_SCORE fuses the GATv2 edge score instead of storing C, and claims the
// edge's CSR slot via atomicAdd(cursor[dst]) so score/psrc land segment-contiguous.
template <bool DO_SCORE>
__global__ __launch_bounds__(256, 2) void gemm160(
    const void* __restrict__ A, long M,
    const __bf16* __restrict__ Bt,
    const __bf16* __restrict__ bias,
    __bf16* __restrict__ Cout,
    const __bf16* __restrict__ xl, const __bf16* __restrict__ xr,
    const int* __restrict__ src, const int* __restrict__ dst,
    const __bf16* __restrict__ att, float* __restrict__ score,
    int* __restrict__ cursor, int* __restrict__ psrc,
    const int* __restrict__ flag)
{
    __shared__ __bf16 Bts[DIM * DIM];   // 51200 B
    __shared__ __bf16 As[128 * 32];     // 8192 B
    const bool aF32 = flag[0] != 0;
    const int tid  = threadIdx.x;
    const int wave = tid >> 6, lane = tid & 63;
    const int quad = lane >> 4, l16 = lane & 15;
    const long blockRow = (long)blockIdx.x * 128;

    {   // stage whole B^T (already canonical bf16)
        const uint4* g = (const uint4*)Bt;
        uint4* s = (uint4*)Bts;
        for (int i = tid; i < DIM * DIM / 8; i += 256) s[i] = g[i];
    }

    const f32x4 zero4 = {0.f, 0.f, 0.f, 0.f};
    f32x4 acc[2][10];
#pragma unroll
    for (int r = 0; r < 2; r++)
#pragma unroll
        for (int n = 0; n < 10; n++) acc[r][n] = zero4;

    for (int k0 = 0; k0 < DIM; k0 += 32) {
        __syncthreads();
        for (int c = tid; c < 512; c += 256) {      // 128x32 tile, 8 elems per chunk
            int row = c >> 2, col = (c & 3) * 8;
            long gr = blockRow + row;
            if (!aF32) {
                uint4 v = {0u, 0u, 0u, 0u};
                if (gr < M) v = *(const uint4*)((const __bf16*)A + gr * DIM + k0 + col);
                ((uint4*)As)[c] = v;
            } else {
                bf16x8 t = {};
                if (gr < M) {
                    const float* ap = (const float*)A + gr * DIM + k0 + col;
                    float4 f0 = *(const float4*)ap;
                    float4 f1 = *(const float4*)(ap + 4);
                    t[0] = (__bf16)f0.x; t[1] = (__bf16)f0.y;
                    t[2] = (__bf16)f0.z; t[3] = (__bf16)f0.w;
                    t[4] = (__bf16)f1.x; t[5] = (__bf16)f1.y;
                    t[6] = (__bf16)f1.z; t[7] = (__bf16)f1.w;
                }
                *(bf16x8*)(((uint4*)As) + c) = t;
            }
        }
        __syncthreads();
        // A frag: lane holds A[m=l16][k=quad*8+j]
        bf16x8 a0 = *(const bf16x8*)(As + (wave * 32 + l16) * 32 + quad * 8);
        bf16x8 a1 = *(const bf16x8*)(As + (wave * 32 + 16 + l16) * 32 + quad * 8);
#pragma unroll
        for (int n = 0; n < 10; n++) {
            // B frag: lane holds B[k=quad*8+j][n=l16] -> contiguous in B^T row
            bf16x8 b = *(const bf16x8*)(Bts + (n * 16 + l16) * DIM + k0 + quad * 8);
            acc[0][n] = __builtin_amdgcn_mfma_f32_16x16x32_bf16(a0, b, acc[0][n], 0, 0, 0);
            acc[1][n] = __builtin_amdgcn_mfma_f32_16x16x32_bf16(a1, b, acc[1][n], 0, 0, 0);
        }
    }

    // C/D layout: col = l16, row = quad*4 + reg
    if (!DO_SCORE) {
#pragma unroll
        for (int r = 0; r < 2; r++)
#pragma unroll
            for (int n = 0; n < 10; n++) {
                int col = n * 16 + l16;
                float bv = (float)bias[col];
#pragma unroll
                for (int reg = 0; reg < 4; reg++) {
                    long row = blockRow + wave * 32 + r * 16 + quad * 4 + reg;
                    if (row < M) Cout[row * DIM + col] = (__bf16)(acc[r][n][reg] + bv);
                }
            }
    } else {
#pragma unroll
        for (int r = 0; r < 2; r++) {
            long erow[4]; int sv[4], dv[4]; int slot[4] = {0, 0, 0, 0};
#pragma unroll
            for (int reg = 0; reg < 4; reg++) {
                erow[reg] = blockRow + wave * 32 + r * 16 + quad * 4 + reg;
                long e = erow[reg] < M ? erow[reg] : M - 1;
                sv[reg] = src[e]; dv[reg] = dst[e];
            }
            if (l16 == 0) {
#pragma unroll
                for (int reg = 0; reg < 4; reg++)
                    if (erow[reg] < M) slot[reg] = atomicAdd(&cursor[dv[reg]], 1);
            }
#pragma unroll
            for (int hh = 0; hh < NHEAD; hh++) {
                float sacc[4] = {0.f, 0.f, 0.f, 0.f};
#pragma unroll
                for (int sub = 0; sub < 2; sub++) {
                    int n = hh * 2 + sub;
                    int col = n * 16 + l16;
                    float av = (float)att[col];   // att[h][c] flat == col
#pragma unroll
                    for (int reg = 0; reg < 4; reg++) {
                        float m = acc[r][n][reg]
                                + (float)xl[(long)sv[reg] * DIM + col]
                                + (float)xr[(long)dv[reg] * DIM + col];
                        m = m > 0.f ? m : 0.2f * m;
                        sacc[reg] += m * av;
                    }
                }
#pragma unroll
                for (int off = 1; off < 16; off <<= 1)
#pragma unroll
                    for (int reg = 0; reg < 4; reg++)
                        sacc[reg] += __shfl_xor(sacc[reg], off, 64);
                if (l16 == 0) {
#pragma unroll
                    for (int reg = 0; reg < 4; reg++)
                        if (erow[reg] < M) score[(long)slot[reg] * NHEAD + hh] = sacc[reg];
                }
            }
            if (l16 == 0) {
#pragma unroll
                for (int reg = 0; reg < 4; reg++)
                    if (erow[reg] < M) psrc[slot[reg]] = sv[reg];
            }
        }
    }
}

__global__ void hist_kernel(const int* __restrict__ dst, int* __restrict__ deg) {
    int e = blockIdx.x * 256 + threadIdx.x;
    if (e < NEDGES) atomicAdd(&deg[dst[e]], 1);
}

__global__ __launch_bounds__(256) void scan_kernel(const int* __restrict__ deg,
                                                   int* __restrict__ offs,
                                                   int* __restrict__ cursor) {
    __shared__ int part[256];
    const int t = threadIdx.x;
    const int chunk = (NNODES + 255) / 256;
    int beg = t * chunk;
    int end = beg + chunk; if (end > NNODES) end = NNODES;
    int s = 0;
    for (int i = beg; i < end; i++) s += deg[i];
    part[t] = s;
    __syncthreads();
    for (int off = 1; off < 256; off <<= 1) {
        int v = 0;
        if (t >= off) v = part[t - off];
        __syncthreads();
        part[t] += v;
        __syncthreads();
    }
    int run = (t == 0) ? 0 : part[t - 1];
    for (int i = beg; i < end; i++) {
        offs[i] = run; cursor[i] = run;
        run += deg[i];
    }
    if (t == 255) offs[NNODES] = run;
}

// One wave per node (4 nodes / 256-thread block). Score/psrc are already
// segment-contiguous (slots claimed in the score-GEMM epilogue), so:
//   pass 1: lane-parallel per-head max (shuffle reduce)
//   pass 2: lane j owns edge j: w[h]=exp(s-mx) once, accumulate UNNORMALIZED
//           w*xl[src] (weights broadcast via shfl), sum of w IS the softmax
//           denominator -> single scale at the end. No serial dependent loads,
//           no per-edge expf recompute, no perm indirection.
__global__ __launch_bounds__(256) void node_kernel(
    const int* __restrict__ offs, const int* __restrict__ psrc,
    const float* __restrict__ score,
    const __bf16* __restrict__ xl, const void* __restrict__ x,
    const __bf16* __restrict__ pb, const int* __restrict__ flag,
    __bf16* __restrict__ hout)
{
    const bool f32 = flag[0] != 0;
    const __bf16* bias  = pb + PB_VEC + 3 * DIM;
    const __bf16* g1    = pb + PB_VEC + 4 * DIM;
    const __bf16* beta1 = pb + PB_VEC + 5 * DIM;
    const int lane = threadIdx.x & 63;
    const long n = (long)blockIdx.x * 4 + (threadIdx.x >> 6);
    const int beg = offs[n], end = offs[n + 1];
    const int deg = end - beg;

    // pass 1: per-head max over incoming edges (lane-parallel, coalesced)
    float mx[NHEAD];
#pragma unroll
    for (int h = 0; h < NHEAD; h++) mx[h] = -1e30f;
    for (int j = lane; j < deg; j += 64) {
        const float* sp = score + (long)(beg + j) * NHEAD;
#pragma unroll
        for (int h = 0; h < NHEAD; h++) mx[h] = fmaxf(mx[h], sp[h]);
    }
#pragma unroll
    for (int h = 0; h < NHEAD; h++)
#pragma unroll
        for (int off = 1; off < 64; off <<= 1)
            mx[h] = fmaxf(mx[h], __shfl_xor(mx[h], off, 64));

    // pass 2: unnormalized weights + weighted accumulation; track per-head sums
    float sm[NHEAD] = {0.f, 0.f, 0.f, 0.f, 0.f};
    float accv[3] = {0.f, 0.f, 0.f};
    for (int j0 = 0; j0 < deg; j0 += 64) {
        const int cn = min(deg - j0, 64);
        float w[NHEAD]; int si = 0;
        if (lane < cn) {
            const float* sp = score + (long)(beg + j0 + lane) * NHEAD;
#pragma unroll
            for (int h = 0; h < NHEAD; h++) {
                w[h] = expf(sp[h] - mx[h]);
                sm[h] += w[h];
            }
            si = psrc[beg + j0 + lane];
        } else {
#pragma unroll
            for (int h = 0; h < NHEAD; h++) w[h] = 0.f;
        }
        for (int j = 0; j < cn; j++) {
            const int sj = __shfl(si, j, 64);
            const float w0 = __shfl(w[0], j, 64);
            const float w1 = __shfl(w[1], j, 64);
            const float w2 = __shfl(w[2], j, 64);
            const float w3 = __shfl(w[3], j, 64);
            const float w4 = __shfl(w[4], j, 64);
            const __bf16* xrow = xl + (long)sj * DIM;
            // ch = lane + c*64 ; head = ch>>5
            accv[0] += (lane < 32 ? w0 : w1) * (float)xrow[lane];
            accv[1] += (lane < 32 ? w2 : w3) * (float)xrow[lane + 64];
            if (lane < 32) accv[2] += w4 * (float)xrow[lane + 128];
        }
    }
#pragma unroll
    for (int h = 0; h < NHEAD; h++)
#pragma unroll
        for (int off = 1; off < 64; off <<= 1)
            sm[h] += __shfl_xor(sm[h], off, 64);
    float ism[NHEAD];
#pragma unroll
    for (int h = 0; h < NHEAD; h++) ism[h] = sm[h] > 0.f ? 1.f / sm[h] : 0.f;
    accv[0] *= lane < 32 ? ism[0] : ism[1];
    accv[1] *= lane < 32 ? ism[2] : ism[3];
    accv[2] *= ism[4];

    // residual + bias + LayerNorm1
    const int nch = (lane < 32) ? 3 : 2;
    float v[3]; float s1 = 0.f, s2 = 0.f;
    for (int c = 0; c < nch; c++) {
        int ch = lane + c * 64;
        float xv = f32 ? ((const float*)x)[n * DIM + ch]
                       : (float)(((const __bf16*)x)[n * DIM + ch]);
        float t = accv[c] + (float)bias[ch] + xv;
        v[c] = t; s1 += t; s2 += t * t;
    }
    for (int off = 1; off < 64; off <<= 1) {
        s1 += __shfl_xor(s1, off, 64);
        s2 += __shfl_xor(s2, off, 64);
    }
    float mu = s1 * (1.f / DIM);
    float var = fmaxf(s2 * (1.f / DIM) - mu * mu, 0.f);
    float rs = rsqrtf(var + 1e-5f);
    for (int c = 0; c < nch; c++) {
        int ch = lane + c * 64;
        hout[n * DIM + ch] = (__bf16)((v[c] - mu) * rs * (float)g1[ch] + (float)beta1[ch]);
    }
}

// per-node MLP: Linear(160,50)->SELU->LN(50)->Linear(50,160)+b2, residual + LN2
// -> ***f32*** out (reference output dtype is float32!)
__global__ __launch_bounds__(256, 2) void mlp_kernel(
    const __bf16* __restrict__ hmat, const __bf16* __restrict__ pb,
    float* __restrict__ out)
{
    __shared__ __bf16 W1s[DIM * MLPH];
    __shared__ __bf16 W2s[MLPH * DIM];
    __shared__ float hrow[4][DIM];
    __shared__ float zrow[4][MLPH];
    const __bf16* W1 = pb + PB_W1;
    const __bf16* W2 = pb + PB_W2;
    const __bf16* b2 = pb + PB_VEC + 6 * DIM;
    const __bf16* g2 = pb + PB_VEC + 7 * DIM;
    const __bf16* beta2 = pb + PB_VEC + 8 * DIM;
    const __bf16* b1 = pb + PB_SMALL;
    const __bf16* gm = pb + PB_SMALL + 50;
    const __bf16* bm = pb + PB_SMALL + 100;
    const int tid = threadIdx.x, wave = tid >> 6, lane = tid & 63;
    for (int i = tid; i < DIM * MLPH / 8; i += 256) {
        ((uint4*)W1s)[i] = ((const uint4*)W1)[i];
        ((uint4*)W2s)[i] = ((const uint4*)W2)[i];
    }
    __syncthreads();
    const int nch = (lane < 32) ? 3 : 2;
    for (int it = 0; it < 4; it++) {
        long n = (long)blockIdx.x * 16 + it * 4 + wave;
        float hv[3];
        for (int c = 0; c < nch; c++) {
            int ch = lane + c * 64;
            float t = (float)hmat[n * DIM + ch];
            hv[c] = t; hrow[wave][ch] = t;
        }
        __syncthreads();
        float z = 0.f;
        if (lane < MLPH) {
            z = (float)b1[lane];
            for (int k = 0; k < DIM; k++) z += hrow[wave][k] * (float)W1s[k * MLPH + lane];
            const float SC = 1.0507009873554805f, AL = 1.6732632423543772f;
            z = (z > 0.f) ? SC * z : SC * AL * (expf(z) - 1.f);
        }
        float s1 = (lane < MLPH) ? z : 0.f, s2 = (lane < MLPH) ? z * z : 0.f;
        for (int off = 1; off < 64; off <<= 1) {
            s1 += __shfl_xor(s1, off, 64);
            s2 += __shfl_xor(s2, off, 64);
        }
        float mu = s1 * (1.f / MLPH);
        float var = fmaxf(s2 * (1.f / MLPH) - mu * mu, 0.f);
        float rs = rsqrtf(var + 1e-5f);
        if (lane < MLPH) zrow[wave][lane] = (z - mu) * rs * (float)gm[lane] + (float)bm[lane];
        __syncthreads();
        float y[3], t1 = 0.f, t2 = 0.f;
        for (int c = 0; c < nch; c++) {
            int ch = lane + c * 64;
            float o = (float)b2[ch];
            for (int j = 0; j < MLPH; j++) o += zrow[wave][j] * (float)W2s[j * DIM + ch];
            float yy = hv[c] + o;
            y[c] = yy; t1 += yy; t2 += yy * yy;
        }
        for (int off = 1; off < 64; off <<= 1) {
            t1 += __shfl_xor(t1, off, 64);
            t2 += __shfl_xor(t2, off, 64);
        }
        float mu2 = t1 * (1.f / DIM);
        float var2 = fmaxf(t2 * (1.f / DIM) - mu2 * mu2, 0.f);
        float rs2 = rsqrtf(var2 + 1e-5f);
        for (int c = 0; c < nch; c++) {
            int ch = lane + c * 64;
            out[n * DIM + ch] = (y[c] - mu2) * rs2 * (float)g2[ch] + (float)beta2[ch];
        }
        __syncthreads();
    }
}

extern "C" void kernel_launch(void* const* d_in, const int* in_sizes, int n_in,
                              void* d_out, int out_size, void* d_ws, size_t ws_size,
                              hipStream_t stream)
{
    const void* x   = d_in[0];
    const int*  ei  = (const int*)d_in[1];
    const void* ea  = d_in[2];
    Ptrs p;
    p.Wl = d_in[5];  p.bl = d_in[6];  p.Wr = d_in[7];  p.br = d_in[8];
    p.We = d_in[9];  p.att = d_in[10]; p.bias = d_in[11];
    p.g1 = d_in[12]; p.beta1 = d_in[13];
    p.W1 = d_in[14]; p.b1 = d_in[15]; p.gm = d_in[16]; p.bm = d_in[17];
    p.W2 = d_in[18]; p.b2 = d_in[19]; p.g2 = d_in[20]; p.beta2 = d_in[21];
    const int* srcp = ei;
    const int* dstp = ei + NEDGES;

    // ---- workspace layout: small/critical buffers FIRST, big arrays last ----
    char* ws = (char*)d_ws;
    int*    flag   = (int*)ws;    ws += 16;
    __bf16* pb     = (__bf16*)ws; ws += (size_t)PB_TOTAL * 2;          // 188,800 B
    int*    deg    = (int*)ws;    ws += (size_t)NNODES * 4;            // 200,000
    int*    offs   = (int*)ws;    ws += (size_t)(NNODES + 1) * 4 + 12; // 200,016
    int*    cursor = (int*)ws;    ws += (size_t)NNODES * 4;            // 200,000
    int*    psrc   = (int*)ws;    ws += (size_t)NEDGES * 4;            // 2,000,000 (was perm)
    float*  score  = (float*)ws;  ws += (size_t)NEDGES * NHEAD * 4;    // 10,000,000
    __bf16* xl     = (__bf16*)ws; ws += (size_t)NNODES * DIM * 2;      // 16,000,000
    __bf16* xr     = (__bf16*)ws; ws += (size_t)NNODES * DIM * 2;      // 16,000,000
    __bf16* hbuf   = xr;  // xr dead after score-gemm; node_kernel writes here
    const size_t NEEDED = (size_t)(ws - (char*)d_ws);

    if (ws_size < NEEDED) {
        // Diagnostic signature: output stays 0 -> absmax ~5.22.
        return;
    }

    (void)hipMemsetAsync(deg, 0, (size_t)NNODES * 4, stream);

    detect_kernel<<<1, 256, 0, stream>>>((const unsigned short*)x, flag);
    prep_kernel<<<369, 256, 0, stream>>>(p, pb, flag);

    const int gemmN = (NNODES + 127) / 128;   // 391
    const int gemmE = (NEDGES + 127) / 128;   // 3907
    gemm160<false><<<gemmN, 256, 0, stream>>>(x, NNODES, pb + PB_WLT, pb + PB_VEC + 0 * DIM, xl,
                                              nullptr, nullptr, nullptr, nullptr, nullptr, nullptr,
                                              nullptr, nullptr, flag);
    gemm160<false><<<gemmN, 256, 0, stream>>>(x, NNODES, pb + PB_WRT, pb + PB_VEC + 1 * DIM, xr,
                                              nullptr, nullptr, nullptr, nullptr, nullptr, nullptr,
                                              nullptr, nullptr, flag);

    hist_kernel<<<(NEDGES + 255) / 256, 256, 0, stream>>>(dstp, deg);
    scan_kernel<<<1, 256, 0, stream>>>(deg, offs, cursor);

    // score GEMM claims CSR slots itself (fill_kernel folded in); writes
    // score + psrc segment-contiguous for node_kernel.
    gemm160<true><<<gemmE, 256, 0, stream>>>(ea, NEDGES, pb + PB_WET, nullptr, nullptr,
                                             xl, xr, srcp, dstp, pb + PB_VEC + 2 * DIM, score,
                                             cursor, psrc, flag);

    node_kernel<<<NNODES / 4, 256, 0, stream>>>(offs, psrc, score, xl, x, pb, flag, hbuf);

    mlp_kernel<<<NNODES / 16, 256, 0, stream>>>(hbuf, pb, (float*)d_out);
}

// Round 2
// 1055.810 us; speedup vs baseline: 1.0282x; 1.0282x over previous
//
#include <hip/hip_runtime.h>

#define NNODES 50000
#define NEDGES 500000
#define DIM    160
#define NHEAD  5
#define MLPH   50

typedef __bf16 bf16x8 __attribute__((ext_vector_type(8)));
typedef float  f32x4  __attribute__((ext_vector_type(4)));

// ---- canonical bf16 param block offsets (elements) ----
#define PB_WLT   0
#define PB_WRT   25600
#define PB_WET   51200
#define PB_W1    76800
#define PB_W2    84800
#define PB_VEC   92800      // bl,br,att,bias,g1,beta1,b2,g2,beta2 (9 x 160)
#define PB_SMALL 94240      // b1(50), gm(50), bm(50)
#define PB_TOTAL 94400

struct Ptrs {
    const void *Wl, *Wr, *We;
    const void *bl, *br, *att, *bias, *g1, *beta1;
    const void *W1, *b1, *gm, *bm, *W2, *b2, *g2, *beta2;
};

__device__ __forceinline__ float ldany(const void* p, long i, bool f32) {
    return f32 ? ((const float*)p)[i] : (float)(((const __bf16*)p)[i]);
}

// Decide whether float tensors are f32 or bf16 bit patterns.
__global__ void detect_kernel(const unsigned short* __restrict__ xs, int* __restrict__ flag) {
    __shared__ int red[4];
    int cnt = 0;
    for (int i = threadIdx.x; i < 65536; i += 256) {
        unsigned e = (xs[i] >> 7) & 0xFFu;
        if (e >= 137u) cnt++;
    }
    for (int off = 1; off < 64; off <<= 1) cnt += __shfl_xor(cnt, off, 64);
    if ((threadIdx.x & 63) == 0) red[threadIdx.x >> 6] = cnt;
    __syncthreads();
    if (threadIdx.x == 0) flag[0] = (red[0] + red[1] + red[2] + red[3] > 1000) ? 1 : 0;
}

// Build canonical bf16 param block: W^T x3, W1, W2, and all bias/scale vectors.
__global__ void prep_kernel(Ptrs p, __bf16* __restrict__ pb, const int* __restrict__ flag) {
    const bool f32 = flag[0] != 0;
    int i = blockIdx.x * 256 + threadIdx.x;
    if (i < 76800) {                       // three 160x160 transposes
        int which = i / 25600, r = i - which * 25600;
        int n = r / DIM, k = r - n * DIM;
        const void* w = which == 0 ? p.Wl : which == 1 ? p.Wr : p.We;
        pb[i] = (__bf16)ldany(w, (long)k * DIM + n, f32);
    } else if (i < 84800) {
        pb[i] = (__bf16)ldany(p.W1, i - PB_W1, f32);
    } else if (i < 92800) {
        pb[i] = (__bf16)ldany(p.W2, i - PB_W2, f32);
    } else if (i < 94240) {
        int t = i - PB_VEC, which = t / DIM, off = t - which * DIM;
        const void* v = which == 0 ? p.bl : which == 1 ? p.br : which == 2 ? p.att :
                        which == 3 ? p.bias : which == 4 ? p.g1 : which == 5 ? p.beta1 :
                        which == 6 ? p.b2 : which == 7 ? p.g2 : p.beta2;
        pb[i] = (__bf16)ldany(v, off, f32);
    } else if (i < 94390) {
        int t = i - PB_SMALL;
        const void* v = t < 50 ? p.b1 : t < 100 ? p.gm : p.bm;
        pb[i] = (__bf16)ldany(v, t % 50, f32);
    }
}

// C[M,160] = A[M,160] @ B[160,160] (+bias) via 16x16x32 bf16 MFMA.
// A fragments are loaded DIRECTLY global->reg (lane l16 owns rows blockRow+w*32+l16
// and +16; each lane reads its own 32B per K-step) with depth-2 register
// prefetch — no A staging in LDS, no per-K-step barriers at all.
// Only B^T lives in LDS, rows padded to 168 elems (bank-conflict-free b128 reads,
// 53760 B -> 3 blocks/CU).
// DO_SCORE fuses the GATv2 edge score and claims the edge's CSR slot via
// atomicAdd(cursor[dst]) so score/psrc land segment-contiguous.
template <bool DO_SCORE>
__global__ __launch_bounds__(256, 3) void gemm160(
    const void* __restrict__ A, long M,
    const __bf16* __restrict__ Bt,
    const __bf16* __restrict__ bias,
    __bf16* __restrict__ Cout,
    const __bf16* __restrict__ xl, const __bf16* __restrict__ xr,
    const int* __restrict__ src, const int* __restrict__ dst,
    const __bf16* __restrict__ att, float* __restrict__ score,
    int* __restrict__ cursor, int* __restrict__ psrc,
    const int* __restrict__ flag)
{
    constexpr int BROW = 168;            // padded LDS row stride (bf16 elems)
    __shared__ __bf16 Bts[DIM * BROW];   // 53760 B
    const bool aF32 = flag[0] != 0;
    const int tid  = threadIdx.x;
    const int wave = tid >> 6, lane = tid & 63;
    const int quad = lane >> 4, l16 = lane & 15;
    const long blockRow = (long)blockIdx.x * 128;

    // each lane owns two A rows; clamp tails (garbage rows only feed masked outputs)
    long row0 = blockRow + wave * 32 + l16;
    long row1 = row0 + 16;
    const long cr0 = row0 < M ? row0 : M - 1;
    const long cr1 = row1 < M ? row1 : M - 1;

    const f32x4 zero4 = {0.f, 0.f, 0.f, 0.f};
    f32x4 acc[2][10];
#pragma unroll
    for (int r = 0; r < 2; r++)
#pragma unroll
        for (int n = 0; n < 10; n++) acc[r][n] = zero4;

    if (aF32) {
        const float* A0 = (const float*)A + cr0 * DIM + quad * 8;
        const float* A1 = (const float*)A + cr1 * DIM + quad * 8;
        float4 buf[2][2][2];             // [parity][r][half]
        // issue first K-step loads, then hide latency under Bts staging
        buf[0][0][0] = *(const float4*)(A0);
        buf[0][0][1] = *(const float4*)(A0 + 4);
        buf[0][1][0] = *(const float4*)(A1);
        buf[0][1][1] = *(const float4*)(A1 + 4);
        for (int i = tid; i < DIM * DIM / 8; i += 256) {
            int row = i / 20, c = i - row * 20;
            *(uint4*)(Bts + row * BROW + c * 8) = ((const uint4*)Bt)[i];
        }
        __syncthreads();
#pragma unroll
        for (int kk = 0; kk < 5; kk++) {
            const int k0 = kk * 32;
            if (kk < 4) {                // prefetch next K-step
                buf[(kk + 1) & 1][0][0] = *(const float4*)(A0 + k0 + 32);
                buf[(kk + 1) & 1][0][1] = *(const float4*)(A0 + k0 + 36);
                buf[(kk + 1) & 1][1][0] = *(const float4*)(A1 + k0 + 32);
                buf[(kk + 1) & 1][1][1] = *(const float4*)(A1 + k0 + 36);
            }
            bf16x8 a0, a1;
            {
                float4 f0 = buf[kk & 1][0][0], f1 = buf[kk & 1][0][1];
                a0[0] = (__bf16)f0.x; a0[1] = (__bf16)f0.y;
                a0[2] = (__bf16)f0.z; a0[3] = (__bf16)f0.w;
                a0[4] = (__bf16)f1.x; a0[5] = (__bf16)f1.y;
                a0[6] = (__bf16)f1.z; a0[7] = (__bf16)f1.w;
                f0 = buf[kk & 1][1][0]; f1 = buf[kk & 1][1][1];
                a1[0] = (__bf16)f0.x; a1[1] = (__bf16)f0.y;
                a1[2] = (__bf16)f0.z; a1[3] = (__bf16)f0.w;
                a1[4] = (__bf16)f1.x; a1[5] = (__bf16)f1.y;
                a1[6] = (__bf16)f1.z; a1[7] = (__bf16)f1.w;
            }
#pragma unroll
            for (int n = 0; n < 10; n++) {
                bf16x8 b = *(const bf16x8*)(Bts + (n * 16 + l16) * BROW + k0 + quad * 8);
                acc[0][n] = __builtin_amdgcn_mfma_f32_16x16x32_bf16(a0, b, acc[0][n], 0, 0, 0);
                acc[1][n] = __builtin_amdgcn_mfma_f32_16x16x32_bf16(a1, b, acc[1][n], 0, 0, 0);
            }
        }
    } else {
        const __bf16* A0 = (const __bf16*)A + cr0 * DIM + quad * 8;
        const __bf16* A1 = (const __bf16*)A + cr1 * DIM + quad * 8;
        bf16x8 af[5][2];
#pragma unroll
        for (int kk = 0; kk < 5; kk++) {   // all K-steps issued up-front (40 VGPRs)
            af[kk][0] = *(const bf16x8*)(A0 + kk * 32);
            af[kk][1] = *(const bf16x8*)(A1 + kk * 32);
        }
        for (int i = tid; i < DIM * DIM / 8; i += 256) {
            int row = i / 20, c = i - row * 20;
            *(uint4*)(Bts + row * BROW + c * 8) = ((const uint4*)Bt)[i];
        }
        __syncthreads();
#pragma unroll
        for (int kk = 0; kk < 5; kk++) {
            const int k0 = kk * 32;
#pragma unroll
            for (int n = 0; n < 10; n++) {
                bf16x8 b = *(const bf16x8*)(Bts + (n * 16 + l16) * BROW + k0 + quad * 8);
                acc[0][n] = __builtin_amdgcn_mfma_f32_16x16x32_bf16(af[kk][0], b, acc[0][n], 0, 0, 0);
                acc[1][n] = __builtin_amdgcn_mfma_f32_16x16x32_bf16(af[kk][1], b, acc[1][n], 0, 0, 0);
            }
        }
    }

    // C/D layout: col = l16, row = quad*4 + reg
    if (!DO_SCORE) {
#pragma unroll
        for (int r = 0; r < 2; r++)
#pragma unroll
            for (int n = 0; n < 10; n++) {
                int col = n * 16 + l16;
                float bv = (float)bias[col];
#pragma unroll
                for (int reg = 0; reg < 4; reg++) {
                    long row = blockRow + wave * 32 + r * 16 + quad * 4 + reg;
                    if (row < M) Cout[row * DIM + col] = (__bf16)(acc[r][n][reg] + bv);
                }
            }
    } else {
#pragma unroll
        for (int r = 0; r < 2; r++) {
            long erow[4]; int sv[4], dv[4]; int slot[4] = {0, 0, 0, 0};
#pragma unroll
            for (int reg = 0; reg < 4; reg++) {
                erow[reg] = blockRow + wave * 32 + r * 16 + quad * 4 + reg;
                long e = erow[reg] < M ? erow[reg] : M - 1;
                sv[reg] = src[e]; dv[reg] = dst[e];
            }
            if (l16 == 0) {
#pragma unroll
                for (int reg = 0; reg < 4; reg++)
                    if (erow[reg] < M) slot[reg] = atomicAdd(&cursor[dv[reg]], 1);
            }
#pragma unroll
            for (int hh = 0; hh < NHEAD; hh++) {
                float sacc[4] = {0.f, 0.f, 0.f, 0.f};
#pragma unroll
                for (int sub = 0; sub < 2; sub++) {
                    int n = hh * 2 + sub;
                    int col = n * 16 + l16;
                    float av = (float)att[col];   // att[h][c] flat == col
#pragma unroll
                    for (int reg = 0; reg < 4; reg++) {
                        float m = acc[r][n][reg]
                                + (float)xl[(long)sv[reg] * DIM + col]
                                + (float)xr[(long)dv[reg] * DIM + col];
                        m = m > 0.f ? m : 0.2f * m;
                        sacc[reg] += m * av;
                    }
                }
#pragma unroll
                for (int off = 1; off < 16; off <<= 1)
#pragma unroll
                    for (int reg = 0; reg < 4; reg++)
                        sacc[reg] += __shfl_xor(sacc[reg], off, 64);
                if (l16 == 0) {
#pragma unroll
                    for (int reg = 0; reg < 4; reg++)
                        if (erow[reg] < M) score[(long)slot[reg] * NHEAD + hh] = sacc[reg];
                }
            }
            if (l16 == 0) {
#pragma unroll
                for (int reg = 0; reg < 4; reg++)
                    if (erow[reg] < M) psrc[slot[reg]] = sv[reg];
            }
        }
    }
}

__global__ void hist_kernel(const int* __restrict__ dst, int* __restrict__ deg) {
    int e = blockIdx.x * 256 + threadIdx.x;
    if (e < NEDGES) atomicAdd(&deg[dst[e]], 1);
}

__global__ __launch_bounds__(1024) void scan_kernel(const int* __restrict__ deg,
                                                    int* __restrict__ offs,
                                                    int* __restrict__ cursor) {
    __shared__ int part[1024];
    const int t = threadIdx.x;
    const int chunk = (NNODES + 1023) / 1024;   // 49
    int beg = t * chunk;
    int end = beg + chunk;
    if (beg > NNODES) beg = NNODES;
    if (end > NNODES) end = NNODES;
    int s = 0;
    for (int i = beg; i < end; i++) s += deg[i];
    part[t] = s;
    __syncthreads();
    for (int off = 1; off < 1024; off <<= 1) {
        int v = 0;
        if (t >= off) v = part[t - off];
        __syncthreads();
        part[t] += v;
        __syncthreads();
    }
    int run = (t == 0) ? 0 : part[t - 1];
    for (int i = beg; i < end; i++) {
        offs[i] = run; cursor[i] = run;
        run += deg[i];
    }
    if (t == 1023) offs[NNODES] = run;
}

// One wave per node (4 nodes / 256-thread block). Score/psrc are already
// segment-contiguous (slots claimed in the score-GEMM epilogue):
//   pass 1: lane-parallel per-head max (shuffle reduce)
//   pass 2: lane j owns edge j: w[h]=exp(s-mx) once, accumulate UNNORMALIZED
//           w*xl[src] (weights broadcast via shfl); sum of w IS the softmax
//           denominator -> single scale at the end.
__global__ __launch_bounds__(256) void node_kernel(
    const int* __restrict__ offs, const int* __restrict__ psrc,
    const float* __restrict__ score,
    const __bf16* __restrict__ xl, const void* __restrict__ x,
    const __bf16* __restrict__ pb, const int* __restrict__ flag,
    __bf16* __restrict__ hout)
{
    const bool f32 = flag[0] != 0;
    const __bf16* bias  = pb + PB_VEC + 3 * DIM;
    const __bf16* g1    = pb + PB_VEC + 4 * DIM;
    const __bf16* beta1 = pb + PB_VEC + 5 * DIM;
    const int lane = threadIdx.x & 63;
    const long n = (long)blockIdx.x * 4 + (threadIdx.x >> 6);
    const int beg = offs[n], end = offs[n + 1];
    const int deg = end - beg;

    float mx[NHEAD];
#pragma unroll
    for (int h = 0; h < NHEAD; h++) mx[h] = -1e30f;
    for (int j = lane; j < deg; j += 64) {
        const float* sp = score + (long)(beg + j) * NHEAD;
#pragma unroll
        for (int h = 0; h < NHEAD; h++) mx[h] = fmaxf(mx[h], sp[h]);
    }
#pragma unroll
    for (int h = 0; h < NHEAD; h++)
#pragma unroll
        for (int off = 1; off < 64; off <<= 1)
            mx[h] = fmaxf(mx[h], __shfl_xor(mx[h], off, 64));

    float sm[NHEAD] = {0.f, 0.f, 0.f, 0.f, 0.f};
    float accv[3] = {0.f, 0.f, 0.f};
    for (int j0 = 0; j0 < deg; j0 += 64) {
        const int cn = min(deg - j0, 64);
        float w[NHEAD]; int si = 0;
        if (lane < cn) {
            const float* sp = score + (long)(beg + j0 + lane) * NHEAD;
#pragma unroll
            for (int h = 0; h < NHEAD; h++) {
                w[h] = expf(sp[h] - mx[h]);
                sm[h] += w[h];
            }
            si = psrc[beg + j0 + lane];
        } else {
#pragma unroll
            for (int h = 0; h < NHEAD; h++) w[h] = 0.f;
        }
        for (int j = 0; j < cn; j++) {
            const int sj = __shfl(si, j, 64);
            const float w0 = __shfl(w[0], j, 64);
            const float w1 = __shfl(w[1], j, 64);
            const float w2 = __shfl(w[2], j, 64);
            const float w3 = __shfl(w[3], j, 64);
            const float w4 = __shfl(w[4], j, 64);
            const __bf16* xrow = xl + (long)sj * DIM;
            accv[0] += (lane < 32 ? w0 : w1) * (float)xrow[lane];
            accv[1] += (lane < 32 ? w2 : w3) * (float)xrow[lane + 64];
            if (lane < 32) accv[2] += w4 * (float)xrow[lane + 128];
        }
    }
#pragma unroll
    for (int h = 0; h < NHEAD; h++)
#pragma unroll
        for (int off = 1; off < 64; off <<= 1)
            sm[h] += __shfl_xor(sm[h], off, 64);
    float ism[NHEAD];
#pragma unroll
    for (int h = 0; h < NHEAD; h++) ism[h] = sm[h] > 0.f ? 1.f / sm[h] : 0.f;
    accv[0] *= lane < 32 ? ism[0] : ism[1];
    accv[1] *= lane < 32 ? ism[2] : ism[3];
    accv[2] *= ism[4];

    const int nch = (lane < 32) ? 3 : 2;
    float v[3]; float s1 = 0.f, s2 = 0.f;
    for (int c = 0; c < nch; c++) {
        int ch = lane + c * 64;
        float xv = f32 ? ((const float*)x)[n * DIM + ch]
                       : (float)(((const __bf16*)x)[n * DIM + ch]);
        float t = accv[c] + (float)bias[ch] + xv;
        v[c] = t; s1 += t; s2 += t * t;
    }
    for (int off = 1; off < 64; off <<= 1) {
        s1 += __shfl_xor(s1, off, 64);
        s2 += __shfl_xor(s2, off, 64);
    }
    float mu = s1 * (1.f / DIM);
    float var = fmaxf(s2 * (1.f / DIM) - mu * mu, 0.f);
    float rs = rsqrtf(var + 1e-5f);
    for (int c = 0; c < nch; c++) {
        int ch = lane + c * 64;
        hout[n * DIM + ch] = (__bf16)((v[c] - mu) * rs * (float)g1[ch] + (float)beta1[ch]);
    }
}

// per-node MLP: Linear(160,50)->SELU->LN(50)->Linear(50,160)+b2, residual + LN2
// -> ***f32*** out (reference output dtype is float32!)
__global__ __launch_bounds__(256, 2) void mlp_kernel(
    const __bf16* __restrict__ hmat, const __bf16* __restrict__ pb,
    float* __restrict__ out)
{
    __shared__ __bf16 W1s[DIM * MLPH];
    __shared__ __bf16 W2s[MLPH * DIM];
    __shared__ float hrow[4][DIM];
    __shared__ float zrow[4][MLPH];
    const __bf16* W1 = pb + PB_W1;
    const __bf16* W2 = pb + PB_W2;
    const __bf16* b2 = pb + PB_VEC + 6 * DIM;
    const __bf16* g2 = pb + PB_VEC + 7 * DIM;
    const __bf16* beta2 = pb + PB_VEC + 8 * DIM;
    const __bf16* b1 = pb + PB_SMALL;
    const __bf16* gm = pb + PB_SMALL + 50;
    const __bf16* bm = pb + PB_SMALL + 100;
    const int tid = threadIdx.x, wave = tid >> 6, lane = tid & 63;
    for (int i = tid; i < DIM * MLPH / 8; i += 256) {
        ((uint4*)W1s)[i] = ((const uint4*)W1)[i];
        ((uint4*)W2s)[i] = ((const uint4*)W2)[i];
    }
    __syncthreads();
    const int nch = (lane < 32) ? 3 : 2;
    for (int it = 0; it < 4; it++) {
        long n = (long)blockIdx.x * 16 + it * 4 + wave;
        float hv[3];
        for (int c = 0; c < nch; c++) {
            int ch = lane + c * 64;
            float t = (float)hmat[n * DIM + ch];
            hv[c] = t; hrow[wave][ch] = t;
        }
        __syncthreads();
        float z = 0.f;
        if (lane < MLPH) {
            z = (float)b1[lane];
            for (int k = 0; k < DIM; k++) z += hrow[wave][k] * (float)W1s[k * MLPH + lane];
            const float SC = 1.0507009873554805f, AL = 1.6732632423543772f;
            z = (z > 0.f) ? SC * z : SC * AL * (expf(z) - 1.f);
        }
        float s1 = (lane < MLPH) ? z : 0.f, s2 = (lane < MLPH) ? z * z : 0.f;
        for (int off = 1; off < 64; off <<= 1) {
            s1 += __shfl_xor(s1, off, 64);
            s2 += __shfl_xor(s2, off, 64);
        }
        float mu = s1 * (1.f / MLPH);
        float var = fmaxf(s2 * (1.f / MLPH) - mu * mu, 0.f);
        float rs = rsqrtf(var + 1e-5f);
        if (lane < MLPH) zrow[wave][lane] = (z - mu) * rs * (float)gm[lane] + (float)bm[lane];
        __syncthreads();
        float y[3], t1 = 0.f, t2 = 0.f;
        for (int c = 0; c < nch; c++) {
            int ch = lane + c * 64;
            float o = (float)b2[ch];
            for (int j = 0; j < MLPH; j++) o += zrow[wave][j] * (float)W2s[j * DIM + ch];
            float yy = hv[c] + o;
            y[c] = yy; t1 += yy; t2 += yy * yy;
        }
        for (int off = 1; off < 64; off <<= 1) {
            t1 += __shfl_xor(t1, off, 64);
            t2 += __shfl_xor(t2, off, 64);
        }
        float mu2 = t1 * (1.f / DIM);
        float var2 = fmaxf(t2 * (1.f / DIM) - mu2 * mu2, 0.f);
        float rs2 = rsqrtf(var2 + 1e-5f);
        for (int c = 0; c < nch; c++) {
            int ch = lane + c * 64;
            out[n * DIM + ch] = (y[c] - mu2) * rs2 * (float)g2[ch] + (float)beta2[ch];
        }
        __syncthreads();
    }
}

extern "C" void kernel_launch(void* const* d_in, const int* in_sizes, int n_in,
                              void* d_out, int out_size, void* d_ws, size_t ws_size,
                              hipStream_t stream)
{
    const void* x   = d_in[0];
    const int*  ei  = (const int*)d_in[1];
    const void* ea  = d_in[2];
    Ptrs p;
    p.Wl = d_in[5];  p.bl = d_in[6];  p.Wr = d_in[7];  p.br = d_in[8];
    p.We = d_in[9];  p.att = d_in[10]; p.bias = d_in[11];
    p.g1 = d_in[12]; p.beta1 = d_in[13];
    p.W1 = d_in[14]; p.b1 = d_in[15]; p.gm = d_in[16]; p.bm = d_in[17];
    p.W2 = d_in[18]; p.b2 = d_in[19]; p.g2 = d_in[20]; p.beta2 = d_in[21];
    const int* srcp = ei;
    const int* dstp = ei + NEDGES;

    // ---- workspace layout: small/critical buffers FIRST, big arrays last ----
    char* ws = (char*)d_ws;
    int*    flag   = (int*)ws;    ws += 16;
    __bf16* pb     = (__bf16*)ws; ws += (size_t)PB_TOTAL * 2;          // 188,800 B
    int*    deg    = (int*)ws;    ws += (size_t)NNODES * 4;            // 200,000
    int*    offs   = (int*)ws;    ws += (size_t)(NNODES + 1) * 4 + 12; // 200,016
    int*    cursor = (int*)ws;    ws += (size_t)NNODES * 4;            // 200,000
    int*    psrc   = (int*)ws;    ws += (size_t)NEDGES * 4;            // 2,000,000
    float*  score  = (float*)ws;  ws += (size_t)NEDGES * NHEAD * 4;    // 10,000,000
    __bf16* xl     = (__bf16*)ws; ws += (size_t)NNODES * DIM * 2;      // 16,000,000
    __bf16* xr     = (__bf16*)ws; ws += (size_t)NNODES * DIM * 2;      // 16,000,000
    __bf16* hbuf   = xr;  // xr dead after score-gemm; node_kernel writes here
    const size_t NEEDED = (size_t)(ws - (char*)d_ws);

    if (ws_size < NEEDED) {
        // Diagnostic signature: output stays 0 -> absmax ~5.22.
        return;
    }

    (void)hipMemsetAsync(deg, 0, (size_t)NNODES * 4, stream);

    detect_kernel<<<1, 256, 0, stream>>>((const unsigned short*)x, flag);
    prep_kernel<<<369, 256, 0, stream>>>(p, pb, flag);

    const int gemmN = (NNODES + 127) / 128;   // 391
    const int gemmE = (NEDGES + 127) / 128;   // 3907
    gemm160<false><<<gemmN, 256, 0, stream>>>(x, NNODES, pb + PB_WLT, pb + PB_VEC + 0 * DIM, xl,
                                              nullptr, nullptr, nullptr, nullptr, nullptr, nullptr,
                                              nullptr, nullptr, flag);
    gemm160<false><<<gemmN, 256, 0, stream>>>(x, NNODES, pb + PB_WRT, pb + PB_VEC + 1 * DIM, xr,
                                              nullptr, nullptr, nullptr, nullptr, nullptr, nullptr,
                                              nullptr, nullptr, flag);

    hist_kernel<<<(NEDGES + 255) / 256, 256, 0, stream>>>(dstp, deg);
    scan_kernel<<<1, 1024, 0, stream>>>(deg, offs, cursor);

    // score GEMM claims CSR slots itself; writes score + psrc segment-contiguous.
    gemm160<true><<<gemmE, 256, 0, stream>>>(ea, NEDGES, pb + PB_WET, nullptr, nullptr,
                                             xl, xr, srcp, dstp, pb + PB_VEC + 2 * DIM, score,
                                             cursor, psrc, flag);

    node_kernel<<<NNODES / 4, 256, 0, stream>>>(offs, psrc, score, xl, x, pb, flag, hbuf);

    mlp_kernel<<<NNODES / 16, 256, 0, stream>>>(hbuf, pb, (float*)d_out);
}

// Round 3
// 1051.093 us; speedup vs baseline: 1.0328x; 1.0045x over previous
//
#include <hip/hip_runtime.h>

#define NNODES 50000
#define NEDGES 500000
#define DIM    160
#define NHEAD  5
#define MLPH   50

typedef __bf16 bf16x8 __attribute__((ext_vector_type(8)));
typedef float  f32x4  __attribute__((ext_vector_type(4)));

// ---- canonical bf16 param block offsets (elements) ----
#define PB_WLT   0
#define PB_WRT   25600
#define PB_WET   51200
#define PB_W1    76800
#define PB_W2    84800
#define PB_VEC   92800      // bl,br,att,bias,g1,beta1,b2,g2,beta2 (9 x 160)
#define PB_SMALL 94240      // b1(50), gm(50), bm(50)
#define PB_TOTAL 94400

struct Ptrs {
    const void *Wl, *Wr, *We;
    const void *bl, *br, *att, *bias, *g1, *beta1;
    const void *W1, *b1, *gm, *bm, *W2, *b2, *g2, *beta2;
};

__device__ __forceinline__ float ldany(const void* p, long i, bool f32) {
    return f32 ? ((const float*)p)[i] : (float)(((const __bf16*)p)[i]);
}

// Decide whether float tensors are f32 or bf16 bit patterns.
__global__ void detect_kernel(const unsigned short* __restrict__ xs, int* __restrict__ flag) {
    __shared__ int red[4];
    int cnt = 0;
    for (int i = threadIdx.x; i < 65536; i += 256) {
        unsigned e = (xs[i] >> 7) & 0xFFu;
        if (e >= 137u) cnt++;
    }
    for (int off = 1; off < 64; off <<= 1) cnt += __shfl_xor(cnt, off, 64);
    if ((threadIdx.x & 63) == 0) red[threadIdx.x >> 6] = cnt;
    __syncthreads();
    if (threadIdx.x == 0) flag[0] = (red[0] + red[1] + red[2] + red[3] > 1000) ? 1 : 0;
}

// Build canonical bf16 param block: W^T x3, W1, W2, and all bias/scale vectors.
__global__ void prep_kernel(Ptrs p, __bf16* __restrict__ pb, const int* __restrict__ flag) {
    const bool f32 = flag[0] != 0;
    int i = blockIdx.x * 256 + threadIdx.x;
    if (i < 76800) {                       // three 160x160 transposes
        int which = i / 25600, r = i - which * 25600;
        int n = r / DIM, k = r - n * DIM;
        const void* w = which == 0 ? p.Wl : which == 1 ? p.Wr : p.We;
        pb[i] = (__bf16)ldany(w, (long)k * DIM + n, f32);
    } else if (i < 84800) {
        pb[i] = (__bf16)ldany(p.W1, i - PB_W1, f32);
    } else if (i < 92800) {
        pb[i] = (__bf16)ldany(p.W2, i - PB_W2, f32);
    } else if (i < 94240) {
        int t = i - PB_VEC, which = t / DIM, off = t - which * DIM;
        const void* v = which == 0 ? p.bl : which == 1 ? p.br : which == 2 ? p.att :
                        which == 3 ? p.bias : which == 4 ? p.g1 : which == 5 ? p.beta1 :
                        which == 6 ? p.b2 : which == 7 ? p.g2 : p.beta2;
        pb[i] = (__bf16)ldany(v, off, f32);
    } else if (i < 94390) {
        int t = i - PB_SMALL;
        const void* v = t < 50 ? p.b1 : t < 100 ? p.gm : p.bm;
        pb[i] = (__bf16)ldany(v, t % 50, f32);
    }
}

// C[M,160] = A[M,160] @ B[160,160] (+bias) via 16x16x32 bf16 MFMA.
// A fragments loaded DIRECTLY global->reg; only B^T in LDS (padded rows).
// DO_SCORE: edges are processed in CSR (dst-sorted) order via perm[] —
//   * A row = ea[perm[csr_slot]]  (640B contiguous rows, gathered)
//   * xr[dst] gathers become cache-hot (consecutive edges share dst)
//   * score/psrc slot == row index -> coalesced stores, NO atomics here.
template <bool DO_SCORE>
__global__ __launch_bounds__(256, 3) void gemm160(
    const void* __restrict__ A, long M,
    const __bf16* __restrict__ Bt,
    const __bf16* __restrict__ bias,
    __bf16* __restrict__ Cout,
    const __bf16* __restrict__ xl, const __bf16* __restrict__ xr,
    const int* __restrict__ perm, const int* __restrict__ psrc,
    const int* __restrict__ dst,
    const __bf16* __restrict__ att, float* __restrict__ score,
    const int* __restrict__ flag)
{
    constexpr int BROW = 168;            // padded LDS row stride (bf16 elems)
    __shared__ __bf16 Bts[DIM * BROW];   // 53760 B
    const bool aF32 = flag[0] != 0;
    const int tid  = threadIdx.x;
    const int wave = tid >> 6, lane = tid & 63;
    const int quad = lane >> 4, l16 = lane & 15;
    const long blockRow = (long)blockIdx.x * 128;

    // each lane owns two A rows; clamp tails (garbage rows only feed masked outputs)
    long row0 = blockRow + wave * 32 + l16;
    long row1 = row0 + 16;
    const long cr0 = row0 < M ? row0 : M - 1;
    const long cr1 = row1 < M ? row1 : M - 1;
    long ar0 = cr0, ar1 = cr1;
    if (DO_SCORE) { ar0 = perm[cr0]; ar1 = perm[cr1]; }   // CSR gather (coalesced perm read)

    // stage whole B^T into padded LDS (overlaps the perm->A dependency latency)
    for (int i = tid; i < DIM * DIM / 8; i += 256) {
        int row = i / 20, c = i - row * 20;
        *(uint4*)(Bts + row * BROW + c * 8) = ((const uint4*)Bt)[i];
    }

    const f32x4 zero4 = {0.f, 0.f, 0.f, 0.f};
    f32x4 acc[2][10];
#pragma unroll
    for (int r = 0; r < 2; r++)
#pragma unroll
        for (int n = 0; n < 10; n++) acc[r][n] = zero4;

    if (aF32) {
        const float* A0 = (const float*)A + ar0 * DIM + quad * 8;
        const float* A1 = (const float*)A + ar1 * DIM + quad * 8;
        float4 buf[2][2][2];             // [parity][r][half]
        buf[0][0][0] = *(const float4*)(A0);
        buf[0][0][1] = *(const float4*)(A0 + 4);
        buf[0][1][0] = *(const float4*)(A1);
        buf[0][1][1] = *(const float4*)(A1 + 4);
        __syncthreads();
#pragma unroll
        for (int kk = 0; kk < 5; kk++) {
            const int k0 = kk * 32;
            if (kk < 4) {                // prefetch next K-step
                buf[(kk + 1) & 1][0][0] = *(const float4*)(A0 + k0 + 32);
                buf[(kk + 1) & 1][0][1] = *(const float4*)(A0 + k0 + 36);
                buf[(kk + 1) & 1][1][0] = *(const float4*)(A1 + k0 + 32);
                buf[(kk + 1) & 1][1][1] = *(const float4*)(A1 + k0 + 36);
            }
            bf16x8 a0, a1;
            {
                float4 f0 = buf[kk & 1][0][0], f1 = buf[kk & 1][0][1];
                a0[0] = (__bf16)f0.x; a0[1] = (__bf16)f0.y;
                a0[2] = (__bf16)f0.z; a0[3] = (__bf16)f0.w;
                a0[4] = (__bf16)f1.x; a0[5] = (__bf16)f1.y;
                a0[6] = (__bf16)f1.z; a0[7] = (__bf16)f1.w;
                f0 = buf[kk & 1][1][0]; f1 = buf[kk & 1][1][1];
                a1[0] = (__bf16)f0.x; a1[1] = (__bf16)f0.y;
                a1[2] = (__bf16)f0.z; a1[3] = (__bf16)f0.w;
                a1[4] = (__bf16)f1.x; a1[5] = (__bf16)f1.y;
                a1[6] = (__bf16)f1.z; a1[7] = (__bf16)f1.w;
            }
#pragma unroll
            for (int n = 0; n < 10; n++) {
                bf16x8 b = *(const bf16x8*)(Bts + (n * 16 + l16) * BROW + k0 + quad * 8);
                acc[0][n] = __builtin_amdgcn_mfma_f32_16x16x32_bf16(a0, b, acc[0][n], 0, 0, 0);
                acc[1][n] = __builtin_amdgcn_mfma_f32_16x16x32_bf16(a1, b, acc[1][n], 0, 0, 0);
            }
        }
    } else {
        const __bf16* A0 = (const __bf16*)A + ar0 * DIM + quad * 8;
        const __bf16* A1 = (const __bf16*)A + ar1 * DIM + quad * 8;
        bf16x8 af[5][2];
#pragma unroll
        for (int kk = 0; kk < 5; kk++) {   // all K-steps issued up-front
            af[kk][0] = *(const bf16x8*)(A0 + kk * 32);
            af[kk][1] = *(const bf16x8*)(A1 + kk * 32);
        }
        __syncthreads();
#pragma unroll
        for (int kk = 0; kk < 5; kk++) {
            const int k0 = kk * 32;
#pragma unroll
            for (int n = 0; n < 10; n++) {
                bf16x8 b = *(const bf16x8*)(Bts + (n * 16 + l16) * BROW + k0 + quad * 8);
                acc[0][n] = __builtin_amdgcn_mfma_f32_16x16x32_bf16(af[kk][0], b, acc[0][n], 0, 0, 0);
                acc[1][n] = __builtin_amdgcn_mfma_f32_16x16x32_bf16(af[kk][1], b, acc[1][n], 0, 0, 0);
            }
        }
    }

    // C/D layout: col = l16, row = quad*4 + reg
    if (!DO_SCORE) {
#pragma unroll
        for (int r = 0; r < 2; r++)
#pragma unroll
            for (int n = 0; n < 10; n++) {
                int col = n * 16 + l16;
                float bv = (float)bias[col];
#pragma unroll
                for (int reg = 0; reg < 4; reg++) {
                    long row = blockRow + wave * 32 + r * 16 + quad * 4 + reg;
                    if (row < M) Cout[row * DIM + col] = (__bf16)(acc[r][n][reg] + bv);
                }
            }
    } else {
#pragma unroll
        for (int r = 0; r < 2; r++) {
            long erow[4]; int sv[4], dv[4];
#pragma unroll
            for (int reg = 0; reg < 4; reg++) {
                erow[reg] = blockRow + wave * 32 + r * 16 + quad * 4 + reg;
                long e = erow[reg] < M ? erow[reg] : M - 1;
                sv[reg] = psrc[e];          // sequential (CSR order)
                dv[reg] = dst[perm[e]];     // coalesced perm + L2-hot dst
            }
#pragma unroll
            for (int hh = 0; hh < NHEAD; hh++) {
                float sacc[4] = {0.f, 0.f, 0.f, 0.f};
#pragma unroll
                for (int sub = 0; sub < 2; sub++) {
                    int n = hh * 2 + sub;
                    int col = n * 16 + l16;
                    float av = (float)att[col];   // att[h][c] flat == col
#pragma unroll
                    for (int reg = 0; reg < 4; reg++) {
                        float m = acc[r][n][reg]
                                + (float)xl[(long)sv[reg] * DIM + col]
                                + (float)xr[(long)dv[reg] * DIM + col];
                        m = m > 0.f ? m : 0.2f * m;
                        sacc[reg] += m * av;
                    }
                }
#pragma unroll
                for (int off = 1; off < 16; off <<= 1)
#pragma unroll
                    for (int reg = 0; reg < 4; reg++)
                        sacc[reg] += __shfl_xor(sacc[reg], off, 64);
                if (l16 == 0) {
#pragma unroll
                    for (int reg = 0; reg < 4; reg++)
                        if (erow[reg] < M) score[erow[reg] * NHEAD + hh] = sacc[reg];
                }
            }
        }
    }
}

__global__ void hist_kernel(const int* __restrict__ dst, int* __restrict__ deg) {
    int e = blockIdx.x * 256 + threadIdx.x;
    if (e < NEDGES) atomicAdd(&deg[dst[e]], 1);
}

__global__ __launch_bounds__(1024) void scan_kernel(const int* __restrict__ deg,
                                                    int* __restrict__ offs,
                                                    int* __restrict__ cursor) {
    __shared__ int part[1024];
    const int t = threadIdx.x;
    const int chunk = (NNODES + 1023) / 1024;   // 49
    int beg = t * chunk;
    int end = beg + chunk;
    if (beg > NNODES) beg = NNODES;
    if (end > NNODES) end = NNODES;
    int s = 0;
    for (int i = beg; i < end; i++) s += deg[i];
    part[t] = s;
    __syncthreads();
    for (int off = 1; off < 1024; off <<= 1) {
        int v = 0;
        if (t >= off) v = part[t - off];
        __syncthreads();
        part[t] += v;
        __syncthreads();
    }
    int run = (t == 0) ? 0 : part[t - 1];
    for (int i = beg; i < end; i++) {
        offs[i] = run; cursor[i] = run;
        run += deg[i];
    }
    if (t == 1023) offs[NNODES] = run;
}

// Scatter edges into CSR order: perm[slot]=edge, psrc[slot]=src[edge].
__global__ void fill_kernel(const int* __restrict__ src, const int* __restrict__ dst,
                            int* __restrict__ cursor, int* __restrict__ perm,
                            int* __restrict__ psrc) {
    int e = blockIdx.x * 256 + threadIdx.x;
    if (e < NEDGES) {
        int p = atomicAdd(&cursor[dst[e]], 1);
        perm[p] = e;
        psrc[p] = src[e];
    }
}

// One wave per node (4 nodes / 256-thread block). Score/psrc are CSR-contiguous:
//   pass 1: lane-parallel per-head max (shuffle reduce)
//   pass 2: lane j owns edge j: w[h]=exp(s-mx) once, accumulate UNNORMALIZED
//           w*xl[src] (weights broadcast via shfl); sum of w IS the softmax
//           denominator -> single scale at the end.
__global__ __launch_bounds__(256) void node_kernel(
    const int* __restrict__ offs, const int* __restrict__ psrc,
    const float* __restrict__ score,
    const __bf16* __restrict__ xl, const void* __restrict__ x,
    const __bf16* __restrict__ pb, const int* __restrict__ flag,
    __bf16* __restrict__ hout)
{
    const bool f32 = flag[0] != 0;
    const __bf16* bias  = pb + PB_VEC + 3 * DIM;
    const __bf16* g1    = pb + PB_VEC + 4 * DIM;
    const __bf16* beta1 = pb + PB_VEC + 5 * DIM;
    const int lane = threadIdx.x & 63;
    const long n = (long)blockIdx.x * 4 + (threadIdx.x >> 6);
    const int beg = offs[n], end = offs[n + 1];
    const int deg = end - beg;

    float mx[NHEAD];
#pragma unroll
    for (int h = 0; h < NHEAD; h++) mx[h] = -1e30f;
    for (int j = lane; j < deg; j += 64) {
        const float* sp = score + (long)(beg + j) * NHEAD;
#pragma unroll
        for (int h = 0; h < NHEAD; h++) mx[h] = fmaxf(mx[h], sp[h]);
    }
#pragma unroll
    for (int h = 0; h < NHEAD; h++)
#pragma unroll
        for (int off = 1; off < 64; off <<= 1)
            mx[h] = fmaxf(mx[h], __shfl_xor(mx[h], off, 64));

    float sm[NHEAD] = {0.f, 0.f, 0.f, 0.f, 0.f};
    float accv[3] = {0.f, 0.f, 0.f};
    for (int j0 = 0; j0 < deg; j0 += 64) {
        const int cn = min(deg - j0, 64);
        float w[NHEAD]; int si = 0;
        if (lane < cn) {
            const float* sp = score + (long)(beg + j0 + lane) * NHEAD;
#pragma unroll
            for (int h = 0; h < NHEAD; h++) {
                w[h] = expf(sp[h] - mx[h]);
                sm[h] += w[h];
            }
            si = psrc[beg + j0 + lane];
        } else {
#pragma unroll
            for (int h = 0; h < NHEAD; h++) w[h] = 0.f;
        }
        for (int j = 0; j < cn; j++) {
            const int sj = __shfl(si, j, 64);
            const float w0 = __shfl(w[0], j, 64);
            const float w1 = __shfl(w[1], j, 64);
            const float w2 = __shfl(w[2], j, 64);
            const float w3 = __shfl(w[3], j, 64);
            const float w4 = __shfl(w[4], j, 64);
            const __bf16* xrow = xl + (long)sj * DIM;
            accv[0] += (lane < 32 ? w0 : w1) * (float)xrow[lane];
            accv[1] += (lane < 32 ? w2 : w3) * (float)xrow[lane + 64];
            if (lane < 32) accv[2] += w4 * (float)xrow[lane + 128];
        }
    }
#pragma unroll
    for (int h = 0; h < NHEAD; h++)
#pragma unroll
        for (int off = 1; off < 64; off <<= 1)
            sm[h] += __shfl_xor(sm[h], off, 64);
    float ism[NHEAD];
#pragma unroll
    for (int h = 0; h < NHEAD; h++) ism[h] = sm[h] > 0.f ? 1.f / sm[h] : 0.f;
    accv[0] *= lane < 32 ? ism[0] : ism[1];
    accv[1] *= lane < 32 ? ism[2] : ism[3];
    accv[2] *= ism[4];

    const int nch = (lane < 32) ? 3 : 2;
    float v[3]; float s1 = 0.f, s2 = 0.f;
    for (int c = 0; c < nch; c++) {
        int ch = lane + c * 64;
        float xv = f32 ? ((const float*)x)[n * DIM + ch]
                       : (float)(((const __bf16*)x)[n * DIM + ch]);
        float t = accv[c] + (float)bias[ch] + xv;
        v[c] = t; s1 += t; s2 += t * t;
    }
    for (int off = 1; off < 64; off <<= 1) {
        s1 += __shfl_xor(s1, off, 64);
        s2 += __shfl_xor(s2, off, 64);
    }
    float mu = s1 * (1.f / DIM);
    float var = fmaxf(s2 * (1.f / DIM) - mu * mu, 0.f);
    float rs = rsqrtf(var + 1e-5f);
    for (int c = 0; c < nch; c++) {
        int ch = lane + c * 64;
        hout[n * DIM + ch] = (__bf16)((v[c] - mu) * rs * (float)g1[ch] + (float)beta1[ch]);
    }
}

// per-node MLP: Linear(160,50)->SELU->LN(50)->Linear(50,160)+b2, residual + LN2
// -> ***f32*** out (reference output dtype is float32!)
__global__ __launch_bounds__(256, 2) void mlp_kernel(
    const __bf16* __restrict__ hmat, const __bf16* __restrict__ pb,
    float* __restrict__ out)
{
    __shared__ __bf16 W1s[DIM * MLPH];
    __shared__ __bf16 W2s[MLPH * DIM];
    __shared__ float hrow[4][DIM];
    __shared__ float zrow[4][MLPH];
    const __bf16* W1 = pb + PB_W1;
    const __bf16* W2 = pb + PB_W2;
    const __bf16* b2 = pb + PB_VEC + 6 * DIM;
    const __bf16* g2 = pb + PB_VEC + 7 * DIM;
    const __bf16* beta2 = pb + PB_VEC + 8 * DIM;
    const __bf16* b1 = pb + PB_SMALL;
    const __bf16* gm = pb + PB_SMALL + 50;
    const __bf16* bm = pb + PB_SMALL + 100;
    const int tid = threadIdx.x, wave = tid >> 6, lane = tid & 63;
    for (int i = tid; i < DIM * MLPH / 8; i += 256) {
        ((uint4*)W1s)[i] = ((const uint4*)W1)[i];
        ((uint4*)W2s)[i] = ((const uint4*)W2)[i];
    }
    __syncthreads();
    const int nch = (lane < 32) ? 3 : 2;
    for (int it = 0; it < 4; it++) {
        long n = (long)blockIdx.x * 16 + it * 4 + wave;
        float hv[3];
        for (int c = 0; c < nch; c++) {
            int ch = lane + c * 64;
            float t = (float)hmat[n * DIM + ch];
            hv[c] = t; hrow[wave][ch] = t;
        }
        __syncthreads();
        float z = 0.f;
        if (lane < MLPH) {
            z = (float)b1[lane];
            for (int k = 0; k < DIM; k++) z += hrow[wave][k] * (float)W1s[k * MLPH + lane];
            const float SC = 1.0507009873554805f, AL = 1.6732632423543772f;
            z = (z > 0.f) ? SC * z : SC * AL * (expf(z) - 1.f);
        }
        float s1 = (lane < MLPH) ? z : 0.f, s2 = (lane < MLPH) ? z * z : 0.f;
        for (int off = 1; off < 64; off <<= 1) {
            s1 += __shfl_xor(s1, off, 64);
            s2 += __shfl_xor(s2, off, 64);
        }
        float mu = s1 * (1.f / MLPH);
        float var = fmaxf(s2 * (1.f / MLPH) - mu * mu, 0.f);
        float rs = rsqrtf(var + 1e-5f);
        if (lane < MLPH) zrow[wave][lane] = (z - mu) * rs * (float)gm[lane] + (float)bm[lane];
        __syncthreads();
        float y[3], t1 = 0.f, t2 = 0.f;
        for (int c = 0; c < nch; c++) {
            int ch = lane + c * 64;
            float o = (float)b2[ch];
            for (int j = 0; j < MLPH; j++) o += zrow[wave][j] * (float)W2s[j * DIM + ch];
            float yy = hv[c] + o;
            y[c] = yy; t1 += yy; t2 += yy * yy;
        }
        for (int off = 1; off < 64; off <<= 1) {
            t1 += __shfl_xor(t1, off, 64);
            t2 += __shfl_xor(t2, off, 64);
        }
        float mu2 = t1 * (1.f / DIM);
        float var2 = fmaxf(t2 * (1.f / DIM) - mu2 * mu2, 0.f);
        float rs2 = rsqrtf(var2 + 1e-5f);
        for (int c = 0; c < nch; c++) {
            int ch = lane + c * 64;
            out[n * DIM + ch] = (y[c] - mu2) * rs2 * (float)g2[ch] + (float)beta2[ch];
        }
        __syncthreads();
    }
}

extern "C" void kernel_launch(void* const* d_in, const int* in_sizes, int n_in,
                              void* d_out, int out_size, void* d_ws, size_t ws_size,
                              hipStream_t stream)
{
    const void* x   = d_in[0];
    const int*  ei  = (const int*)d_in[1];
    const void* ea  = d_in[2];
    Ptrs p;
    p.Wl = d_in[5];  p.bl = d_in[6];  p.Wr = d_in[7];  p.br = d_in[8];
    p.We = d_in[9];  p.att = d_in[10]; p.bias = d_in[11];
    p.g1 = d_in[12]; p.beta1 = d_in[13];
    p.W1 = d_in[14]; p.b1 = d_in[15]; p.gm = d_in[16]; p.bm = d_in[17];
    p.W2 = d_in[18]; p.b2 = d_in[19]; p.g2 = d_in[20]; p.beta2 = d_in[21];
    const int* srcp = ei;
    const int* dstp = ei + NEDGES;

    // ---- workspace layout: small/critical buffers FIRST, big arrays last ----
    char* ws = (char*)d_ws;
    int*    flag   = (int*)ws;    ws += 16;
    __bf16* pb     = (__bf16*)ws; ws += (size_t)PB_TOTAL * 2;          // 188,800 B
    int*    deg    = (int*)ws;    ws += (size_t)NNODES * 4;            // 200,000
    int*    offs   = (int*)ws;    ws += (size_t)(NNODES + 1) * 4 + 12; // 200,016
    int*    cursor = (int*)ws;    ws += (size_t)NNODES * 4;            // 200,000
    int*    perm   = (int*)ws;    ws += (size_t)NEDGES * 4;            // 2,000,000
    int*    psrc   = (int*)ws;    ws += (size_t)NEDGES * 4;            // 2,000,000
    float*  score  = (float*)ws;  ws += (size_t)NEDGES * NHEAD * 4;    // 10,000,000
    __bf16* xl     = (__bf16*)ws; ws += (size_t)NNODES * DIM * 2;      // 16,000,000
    __bf16* xr     = (__bf16*)ws; ws += (size_t)NNODES * DIM * 2;      // 16,000,000
    __bf16* hbuf   = xr;  // xr dead after score-gemm; node_kernel writes here
    const size_t NEEDED = (size_t)(ws - (char*)d_ws);

    if (ws_size < NEEDED) {
        // Diagnostic signature: output stays 0 -> absmax ~5.22.
        return;
    }

    (void)hipMemsetAsync(deg, 0, (size_t)NNODES * 4, stream);

    detect_kernel<<<1, 256, 0, stream>>>((const unsigned short*)x, flag);
    prep_kernel<<<369, 256, 0, stream>>>(p, pb, flag);

    const int gemmN = (NNODES + 127) / 128;   // 391
    const int gemmE = (NEDGES + 127) / 128;   // 3907
    gemm160<false><<<gemmN, 256, 0, stream>>>(x, NNODES, pb + PB_WLT, pb + PB_VEC + 0 * DIM, xl,
                                              nullptr, nullptr, nullptr, nullptr, nullptr,
                                              nullptr, nullptr, flag);
    gemm160<false><<<gemmN, 256, 0, stream>>>(x, NNODES, pb + PB_WRT, pb + PB_VEC + 1 * DIM, xr,
                                              nullptr, nullptr, nullptr, nullptr, nullptr,
                                              nullptr, nullptr, flag);

    hist_kernel<<<(NEDGES + 255) / 256, 256, 0, stream>>>(dstp, deg);
    scan_kernel<<<1, 1024, 0, stream>>>(deg, offs, cursor);
    fill_kernel<<<(NEDGES + 255) / 256, 256, 0, stream>>>(srcp, dstp, cursor, perm, psrc);

    // score GEMM in CSR order: coalesced score writes, cache-hot xr gathers, no atomics.
    gemm160<true><<<gemmE, 256, 0, stream>>>(ea, NEDGES, pb + PB_WET, nullptr, nullptr,
                                             xl, xr, perm, psrc, dstp,
                                             pb + PB_VEC + 2 * DIM, score, flag);

    node_kernel<<<NNODES / 4, 256, 0, stream>>>(offs, psrc, score, xl, x, pb, flag, hbuf);

    mlp_kernel<<<NNODES / 16, 256, 0, stream>>>(hbuf, pb, (float*)d_out);
}